// Round 10
// baseline (103.858 us; speedup 1.0000x reference)
//
#include <hip/hip_runtime.h>
#include <math.h>

#define BB 4
#define NN 128
#define LK 16384      // n*n
#define DD 64
#define HH 4
#define DHH 16
#define TI2 32        // q-rows per block
#define QK_SCALE 0.3606737602f   // 0.25 * log2(e): exp(d/4) == exp2(d*QK_SCALE)

__device__ __forceinline__ float fexp2(float x){
#if __has_builtin(__builtin_amdgcn_exp2f)
  return __builtin_amdgcn_exp2f(x);   // v_exp_f32
#else
  return __expf(x * 0.6931471806f);
#endif
}

// ---- mask dtype classification via wave ballots: 0=int32, 1=uint8, 2=float32
__device__ __forceinline__ int compute_mode(const void* __restrict__ qmask){
  const unsigned int* w = (const unsigned int*)qmask;
  const int t = threadIdx.x & 63;
  int u8 = 0, i32 = 0, f32 = 0;
  #pragma unroll
  for (int rep = 0; rep < 2; ++rep){
    const unsigned int x = w[t + rep*64];   // first 512B: in-bounds for every dtype
    const bool one  = (x == 1u);
    const bool fone = (x == 0x3f800000u);
    const bool nz   = (x != 0u);
    u8  += __popcll(__ballot(nz && !one && !fone));
    i32 += __popcll(__ballot(one));
    f32 += __popcll(__ballot(fone));
  }
  int mode = 0;
  if (u8 > i32 && u8 > f32) mode = 1;
  else if (f32 > i32) mode = 2;
  return mode;
}

__device__ __forceinline__ bool mget(const void* __restrict__ p, int idx, int mode){
  if (mode == 1) return ((const unsigned char*)p)[idx] != 0;
  if (mode == 2) return ((const float*)p)[idx] != 0.0f;
  return ((const int*)p)[idx] != 0;
}

__device__ __forceinline__ float dot16(float4 q0, float4 q1, float4 q2, float4 q3,
                                       float4 k0, float4 k1, float4 k2, float4 k3){
  float d;
  d = q0.x*k0.x;         d = fmaf(q0.y,k0.y,d); d = fmaf(q0.z,k0.z,d); d = fmaf(q0.w,k0.w,d);
  d = fmaf(q1.x,k1.x,d); d = fmaf(q1.y,k1.y,d); d = fmaf(q1.z,k1.z,d); d = fmaf(q1.w,k1.w,d);
  d = fmaf(q2.x,k2.x,d); d = fmaf(q2.y,k2.y,d); d = fmaf(q2.z,k2.z,d); d = fmaf(q2.w,k2.w,d);
  d = fmaf(q3.x,k3.x,d); d = fmaf(q3.y,k3.y,d); d = fmaf(q3.z,k3.z,d); d = fmaf(q3.w,k3.w,d);
  return d;
}

// stage TI2 q-rows, pre-scaled by QK_SCALE (fully coalesced)
__device__ __forceinline__ void stage_q(const float* __restrict__ qA, int b, int ibase,
                                        float* __restrict__ ldsQ){
  const int t = threadIdx.x;
  const float4* src = (const float4*)(qA + ((size_t)(b*NN + ibase))*DD);
  #pragma unroll
  for (int p = 0; p < 2; ++p){
    const int f = p*256 + t;          // 0..511 over 8KB
    float4 v = src[f];
    v.x *= QK_SCALE; v.y *= QK_SCALE; v.z *= QK_SCALE; v.w *= QK_SCALE;
    *(float4*)(ldsQ + (f >> 4)*DD + (f & 15)*4) = v;
  }
}

// ---- pass 1: per-(h,row) sum of exp2 over this block's 256-l span ----
// Mirror of the proven K2 structure: lane owns 4 consecutive l (k in 64 VGPRs,
// one-time global load), q from 8KB ldsQ broadcast, no k-staging, no mid-loop
// barriers. i-loop split into 2 rounds of 16 (s[16] live) to cap VGPR.
__global__ __launch_bounds__(256) void k1_rowsum(
    const float* __restrict__ qA, const float* __restrict__ kA,
    const void* __restrict__ qm, const void* __restrict__ km,
    float* __restrict__ partials)
{
  __shared__ float ldsQ[TI2*DD];       // 8 KB
  __shared__ float ldsP[HH][16];
  const int mode = compute_mode(qm);
  const int lc = blockIdx.x, it = blockIdx.y, b = blockIdx.z;
  const int t = threadIdx.x, w = t >> 6, ll = t & 63;
  const int ibase = it*TI2;
  const int lbase = lc*256 + ll*4;     // this lane's first l

  stage_q(qA, b, ibase, ldsQ);

  // k for 4 consecutive rows (own head) straight from global (one-time, L2-hot)
  float4 kk[4][4];
  #pragma unroll
  for (int e = 0; e < 4; ++e){
    const float4* kp = (const float4*)(kA + ((size_t)(b*LK + lbase + e))*DD + w*DHH);
    #pragma unroll
    for (int p = 0; p < 4; ++p) kk[e][p] = kp[p];
  }

  unsigned vm[4];
  #pragma unroll
  for (int e = 0; e < 4; ++e){
    const int l = lbase + e;
    const int jn = l >> 7, kn = l & 127;
    const bool kv = (jn != kn) && mget(km, b*LK + l, mode);
    unsigned m = kv ? 0xFFFFFFFFu : 0u;
    if ((unsigned)(jn - ibase) < TI2) m &= ~(1u << (jn - ibase));
    if ((unsigned)(kn - ibase) < TI2) m &= ~(1u << (kn - ibase));
    vm[e] = m;
  }
  __syncthreads();

  #pragma unroll
  for (int r = 0; r < 2; ++r){         // 2 rounds x 16 rows: caps live s[] regs
    float s[16];
    #pragma unroll
    for (int ii = 0; ii < 16; ++ii) s[ii] = 0.0f;

    #pragma unroll
    for (int ii = 0; ii < 16; ++ii){
      const int i = r*16 + ii;
      const float* qp = ldsQ + i*DD + w*DHH;   // wave-uniform -> LDS broadcast
      const float4 q0 = *(const float4*)(qp),   q1 = *(const float4*)(qp+4),
                   q2 = *(const float4*)(qp+8), q3 = *(const float4*)(qp+12);
      float d0 = dot16(q0,q1,q2,q3, kk[0][0],kk[0][1],kk[0][2],kk[0][3]);
      float d1 = dot16(q0,q1,q2,q3, kk[1][0],kk[1][1],kk[1][2],kk[1][3]);
      float d2 = dot16(q0,q1,q2,q3, kk[2][0],kk[2][1],kk[2][2],kk[2][3]);
      float d3 = dot16(q0,q1,q2,q3, kk[3][0],kk[3][1],kk[3][2],kk[3][3]);
      d0 = ((vm[0] >> i) & 1u) ? d0 : -INFINITY;   // exp2(-inf)=0
      d1 = ((vm[1] >> i) & 1u) ? d1 : -INFINITY;
      d2 = ((vm[2] >> i) & 1u) ? d2 : -INFINITY;
      d3 = ((vm[3] >> i) & 1u) ? d3 : -INFINITY;
      s[ii] += (fexp2(d0) + fexp2(d1)) + (fexp2(d2) + fexp2(d3));
    }

    // wave w covers head w's full 256-l span: 64-lane reduce completes the sum
    #pragma unroll
    for (int ii = 0; ii < 16; ++ii){
      float v = s[ii];
      #pragma unroll
      for (int off = 32; off; off >>= 1) v += __shfl_xor(v, off);
      if (ll == 0) ldsP[w][ii] = v;
    }
    __syncthreads();
    if (t < HH*16){                    // t = h*16 + ii
      const int h = t >> 4, ii = t & 15;
      const int i = r*16 + ii;
      const bool qv = mget(qm, b*NN + ibase + i, mode);
      partials[((lc*BB + b)*HH + h)*NN + ibase + i] = qv ? ldsP[h][ii] : 0.0f;
    }
    if (r == 0) __syncthreads();       // protect ldsP for round 1
  }
}

// ---- pass 1b: reduce partials over lc -> reciprocal row sums ----
__global__ void k1_finalize(const float* __restrict__ partials, float* __restrict__ R){
  const int tid = blockIdx.x*256 + threadIdx.x;   // 0..2047 = (b*HH+h)*NN+ig
  float ssum = 0.0f;
  for (int lc = 0; lc < LK/256; ++lc) ssum += partials[lc*(BB*HH*NN) + tid];
  R[tid] = (ssum > 0.0f) ? 1.0f/ssum : 0.0f;
}

// ---- pass 2: lane owns 4 consecutive l (k in 64 VGPRs); q+R from small LDS;
// float4 stores (1KB/wave contiguous). Byte-identical to R9.
__global__ __launch_bounds__(256) void k2_emit(
    const float* __restrict__ qA, const float* __restrict__ kA,
    const void* __restrict__ qm, const void* __restrict__ km,
    const float* __restrict__ R, float* __restrict__ out)
{
  __shared__ float ldsQ[TI2*DD];       // 8 KB
  __shared__ float ldsR[HH*TI2];       // 512 B
  const int mode = compute_mode(qm);
  const int lc = blockIdx.x, it = blockIdx.y, b = blockIdx.z;
  const int t = threadIdx.x, w = t >> 6, ll = t & 63;
  const int ibase = it*TI2;
  const int lbase = lc*256 + ll*4;     // this lane's first l

  stage_q(qA, b, ibase, ldsQ);
  if (t < HH*TI2){                     // t = h*32 + i
    ldsR[t] = R[(b*HH + (t >> 5))*NN + ibase + (t & 31)];
  }

  float4 kk[4][4];
  #pragma unroll
  for (int e = 0; e < 4; ++e){
    const float4* kp = (const float4*)(kA + ((size_t)(b*LK + lbase + e))*DD + w*DHH);
    #pragma unroll
    for (int p = 0; p < 4; ++p) kk[e][p] = kp[p];
  }

  unsigned vm[4];
  #pragma unroll
  for (int e = 0; e < 4; ++e){
    const int l = lbase + e;
    const int jn = l >> 7, kn = l & 127;
    const bool kv = (jn != kn) && mget(km, b*LK + l, mode);
    unsigned m = kv ? 0xFFFFFFFFu : 0u;
    if ((unsigned)(jn - ibase) < TI2) m &= ~(1u << (jn - ibase));
    if ((unsigned)(kn - ibase) < TI2) m &= ~(1u << (kn - ibase));
    vm[e] = m;   // q-mask not needed: masked q-rows have R==0
  }
  __syncthreads();

  float* op = out + (((size_t)((w*BB + b)*NN + ibase)) << 14) + lbase;

  #pragma unroll 2
  for (int i = 0; i < TI2; ++i){
    const float* qp = ldsQ + i*DD + w*DHH;     // wave-uniform -> LDS broadcast
    const float4 q0 = *(const float4*)(qp),   q1 = *(const float4*)(qp+4),
                 q2 = *(const float4*)(qp+8), q3 = *(const float4*)(qp+12);
    const float r = ldsR[w*TI2 + i];           // wave-uniform LDS read
    float4 o;
    o.x = fexp2((vm[0] & (1u<<i)) ? dot16(q0,q1,q2,q3, kk[0][0],kk[0][1],kk[0][2],kk[0][3]) : -INFINITY) * r;
    o.y = fexp2((vm[1] & (1u<<i)) ? dot16(q0,q1,q2,q3, kk[1][0],kk[1][1],kk[1][2],kk[1][3]) : -INFINITY) * r;
    o.z = fexp2((vm[2] & (1u<<i)) ? dot16(q0,q1,q2,q3, kk[2][0],kk[2][1],kk[2][2],kk[2][3]) : -INFINITY) * r;
    o.w = fexp2((vm[3] & (1u<<i)) ? dot16(q0,q1,q2,q3, kk[3][0],kk[3][1],kk[3][2],kk[3][3]) : -INFINITY) * r;
    *(float4*)(op + (((size_t)i) << 14)) = o;  // 64 lanes -> 1KB contiguous
  }
}

extern "C" void kernel_launch(void* const* d_in, const int* in_sizes, int n_in,
                              void* d_out, int out_size, void* d_ws, size_t ws_size,
                              hipStream_t stream)
{
  const float* qA = (const float*)d_in[0];
  const float* kA = (const float*)d_in[1];
  const void*  qm = d_in[2];
  const void*  km = d_in[3];
  float* out = (float*)d_out;

  float* partials = (float*)d_ws;                    // 64*2048 floats = 512KB
  float* R        = partials + (size_t)(LK/256)*BB*HH*NN;

  dim3 g1(LK/256, NN/TI2, BB);     // (64, 4, 4) = 1024 blocks
  k1_rowsum<<<g1, 256, 0, stream>>>(qA, kA, qm, km, partials);
  k1_finalize<<<(BB*HH*NN)/256, 256, 0, stream>>>(partials, R);
  dim3 g2(LK/256, NN/TI2, BB);     // (64, 4, 4) = 1024 blocks
  k2_emit<<<g2, 256, 0, stream>>>(qA, kA, qm, km, R, out);
}

// Round 11
// 73.529 us; speedup vs baseline: 1.4125x; 1.4125x over previous
//
#include <hip/hip_runtime.h>
#include <math.h>

#define BB 4
#define NN 128
#define LK 16384      // n*n
#define DD 64
#define HH 4
#define DHH 16
#define TI2 32        // q-rows per wave/tile
#define KROWS 64      // staged k rows per chunk
#define KPAD 68       // floats per LDS row (272B)
#define QK_SCALE 0.3606737602f   // 0.25 * log2(e): exp(d/4) == exp2(d*QK_SCALE)

__device__ __forceinline__ float fexp2(float x){
#if __has_builtin(__builtin_amdgcn_exp2f)
  return __builtin_amdgcn_exp2f(x);   // v_exp_f32
#else
  return __expf(x * 0.6931471806f);
#endif
}

// ---- mask dtype classification via wave ballots: 0=int32, 1=uint8, 2=float32
__device__ __forceinline__ int compute_mode(const void* __restrict__ qmask){
  const unsigned int* w = (const unsigned int*)qmask;
  const int t = threadIdx.x & 63;
  int u8 = 0, i32 = 0, f32 = 0;
  #pragma unroll
  for (int rep = 0; rep < 2; ++rep){
    const unsigned int x = w[t + rep*64];   // first 512B: in-bounds for every dtype
    const bool one  = (x == 1u);
    const bool fone = (x == 0x3f800000u);
    const bool nz   = (x != 0u);
    u8  += __popcll(__ballot(nz && !one && !fone));
    i32 += __popcll(__ballot(one));
    f32 += __popcll(__ballot(fone));
  }
  int mode = 0;
  if (u8 > i32 && u8 > f32) mode = 1;
  else if (f32 > i32) mode = 2;
  return mode;
}

__device__ __forceinline__ bool mget(const void* __restrict__ p, int idx, int mode){
  if (mode == 1) return ((const unsigned char*)p)[idx] != 0;
  if (mode == 2) return ((const float*)p)[idx] != 0.0f;
  return ((const int*)p)[idx] != 0;
}

__device__ __forceinline__ float dot16(float4 q0, float4 q1, float4 q2, float4 q3,
                                       float4 k0, float4 k1, float4 k2, float4 k3){
  float d;
  d = q0.x*k0.x;         d = fmaf(q0.y,k0.y,d); d = fmaf(q0.z,k0.z,d); d = fmaf(q0.w,k0.w,d);
  d = fmaf(q1.x,k1.x,d); d = fmaf(q1.y,k1.y,d); d = fmaf(q1.z,k1.z,d); d = fmaf(q1.w,k1.w,d);
  d = fmaf(q2.x,k2.x,d); d = fmaf(q2.y,k2.y,d); d = fmaf(q2.z,k2.z,d); d = fmaf(q2.w,k2.w,d);
  d = fmaf(q3.x,k3.x,d); d = fmaf(q3.y,k3.y,d); d = fmaf(q3.z,k3.z,d); d = fmaf(q3.w,k3.w,d);
  return d;
}

// stage TI2 q-rows, pre-scaled by QK_SCALE (256-thread version, K2)
__device__ __forceinline__ void stage_q(const float* __restrict__ qA, int b, int ibase,
                                        float* __restrict__ ldsQ){
  const int t = threadIdx.x;
  const float4* src = (const float4*)(qA + ((size_t)(b*NN + ibase))*DD);
  #pragma unroll
  for (int p = 0; p < 2; ++p){
    const int f = p*256 + t;          // 0..511 over 8KB
    float4 v = src[f];
    v.x *= QK_SCALE; v.y *= QK_SCALE; v.z *= QK_SCALE; v.w *= QK_SCALE;
    *(float4*)(ldsQ + (f >> 4)*DD + (f & 15)*4) = v;
  }
}

// ---- pass 1: per-(h,row) sum of exp2 over this block's 256-l span ----
// 1024-thread block = 16 waves = (head, it-tile): k chunk staged ONCE per block
// (vs 4x in R9). Inner loop is R9's verbatim (s[32], LDS k-frag, q broadcast).
__global__ __launch_bounds__(1024) void k1_rowsum(
    const float* __restrict__ qA, const float* __restrict__ kA,
    const void* __restrict__ qm, const void* __restrict__ km,
    float* __restrict__ partials)
{
  __shared__ float ldsK[KROWS*KPAD];   // 17.4 KB
  __shared__ float ldsQ[NN*DD];        // 32 KB (all 128 q rows)
  __shared__ float ldsP[16][TI2];      // [wave][row] 2 KB
  const int mode = compute_mode(qm);
  const int lc = blockIdx.x, b = blockIdx.y;
  const int t = threadIdx.x, w = t >> 6, ll = t & 63;
  const int h = w & 3, it = w >> 2;    // wave = (head, it-tile)
  const int ibase = it*TI2;

  // stage all 128 q rows, pre-scaled (1024 threads x 2 float4 = 32KB)
  {
    const float4* src = (const float4*)(qA + ((size_t)(b*NN))*DD);
    #pragma unroll
    for (int p = 0; p < 2; ++p){
      const int f = p*1024 + t;
      float4 v = src[f];
      v.x *= QK_SCALE; v.y *= QK_SCALE; v.z *= QK_SCALE; v.w *= QK_SCALE;
      *(float4*)(ldsQ + (f >> 4)*DD + (f & 15)*4) = v;
    }
  }

  float s[TI2];
  #pragma unroll
  for (int i = 0; i < TI2; ++i) s[i] = 0.0f;

  for (int jj = 0; jj < 4; ++jj){
    if (jj) __syncthreads();                 // prior chunk's readers done
    {  // stage 16KB k chunk, once per block: 1 float4 per thread, coalesced
      const float4* src = (const float4*)(kA + ((size_t)(b*LK + lc*256 + jj*KROWS))*DD);
      const float4 v = src[t];
      *(float4*)(ldsK + (t >> 4)*KPAD + (t & 15)*4) = v;
    }
    __syncthreads();

    const int l  = lc*256 + jj*KROWS + ll;
    const int jn = l >> 7, kn = l & 127;
    const bool kv = (jn != kn) && mget(km, (b << 14) + l, mode);
    unsigned vmask = kv ? 0xFFFFFFFFu : 0u;
    if ((unsigned)(jn - ibase) < TI2) vmask &= ~(1u << (jn - ibase));
    if ((unsigned)(kn - ibase) < TI2) vmask &= ~(1u << (kn - ibase));

    const float* kp = ldsK + ll*KPAD + h*DHH;
    const float4 k0 = *(const float4*)(kp),    k1 = *(const float4*)(kp+4),
                 k2 = *(const float4*)(kp+8),  k3 = *(const float4*)(kp+12);

    #pragma unroll
    for (int i = 0; i < TI2; ++i){              // R9-verbatim inner loop
      const float* qp = ldsQ + (ibase + i)*DD + h*DHH;  // wave-uniform -> broadcast
      float d = dot16(*(const float4*)(qp),   *(const float4*)(qp+4),
                      *(const float4*)(qp+8), *(const float4*)(qp+12),
                      k0, k1, k2, k3);
      d = (vmask & (1u << i)) ? d : -INFINITY;  // exp2(-inf)=0
      s[i] += fexp2(d);
    }
  }

  #pragma unroll
  for (int i = 0; i < TI2; ++i){
    float v = s[i];
    #pragma unroll
    for (int off = 32; off; off >>= 1) v += __shfl_xor(v, off);
    if (ll == 0) ldsP[w][i] = v;
  }
  __syncthreads();
  if (t < HH*NN){                  // t = h2*128 + i  (i = global q-row)
    const int h2 = t >> 7, i = t & 127;
    const bool qv = mget(qm, b*NN + i, mode);
    partials[((lc*BB + b)*HH + h2)*NN + i] = qv ? ldsP[(i >> 5)*4 + h2][i & 31] : 0.0f;
  }
}

// ---- pass 1b: reduce partials over lc -> reciprocal row sums ----
__global__ void k1_finalize(const float* __restrict__ partials, float* __restrict__ R){
  const int tid = blockIdx.x*256 + threadIdx.x;   // 0..2047 = (b*HH+h)*NN+ig
  float ssum = 0.0f;
  for (int lc = 0; lc < LK/256; ++lc) ssum += partials[lc*(BB*HH*NN) + tid];
  R[tid] = (ssum > 0.0f) ? 1.0f/ssum : 0.0f;
}

// ---- pass 2: lane owns 4 consecutive l (k in 64 VGPRs); q+R from small LDS;
// float4 stores (1KB/wave contiguous). Byte-identical to R9.
__global__ __launch_bounds__(256) void k2_emit(
    const float* __restrict__ qA, const float* __restrict__ kA,
    const void* __restrict__ qm, const void* __restrict__ km,
    const float* __restrict__ R, float* __restrict__ out)
{
  __shared__ float ldsQ[TI2*DD];       // 8 KB
  __shared__ float ldsR[HH*TI2];       // 512 B
  const int mode = compute_mode(qm);
  const int lc = blockIdx.x, it = blockIdx.y, b = blockIdx.z;
  const int t = threadIdx.x, w = t >> 6, ll = t & 63;
  const int ibase = it*TI2;
  const int lbase = lc*256 + ll*4;     // this lane's first l

  stage_q(qA, b, ibase, ldsQ);
  if (t < HH*TI2){                     // t = h*32 + i
    ldsR[t] = R[(b*HH + (t >> 5))*NN + ibase + (t & 31)];
  }

  float4 kk[4][4];
  #pragma unroll
  for (int e = 0; e < 4; ++e){
    const float4* kp = (const float4*)(kA + ((size_t)(b*LK + lbase + e))*DD + w*DHH);
    #pragma unroll
    for (int p = 0; p < 4; ++p) kk[e][p] = kp[p];
  }

  unsigned vm[4];
  #pragma unroll
  for (int e = 0; e < 4; ++e){
    const int l = lbase + e;
    const int jn = l >> 7, kn = l & 127;
    const bool kv = (jn != kn) && mget(km, b*LK + l, mode);
    unsigned m = kv ? 0xFFFFFFFFu : 0u;
    if ((unsigned)(jn - ibase) < TI2) m &= ~(1u << (jn - ibase));
    if ((unsigned)(kn - ibase) < TI2) m &= ~(1u << (kn - ibase));
    vm[e] = m;   // q-mask not needed: masked q-rows have R==0
  }
  __syncthreads();

  float* op = out + (((size_t)((w*BB + b)*NN + ibase)) << 14) + lbase;

  #pragma unroll 2
  for (int i = 0; i < TI2; ++i){
    const float* qp = ldsQ + i*DD + w*DHH;     // wave-uniform -> LDS broadcast
    const float4 q0 = *(const float4*)(qp),   q1 = *(const float4*)(qp+4),
                 q2 = *(const float4*)(qp+8), q3 = *(const float4*)(qp+12);
    const float r = ldsR[w*TI2 + i];           // wave-uniform LDS read
    float4 o;
    o.x = fexp2((vm[0] & (1u<<i)) ? dot16(q0,q1,q2,q3, kk[0][0],kk[0][1],kk[0][2],kk[0][3]) : -INFINITY) * r;
    o.y = fexp2((vm[1] & (1u<<i)) ? dot16(q0,q1,q2,q3, kk[1][0],kk[1][1],kk[1][2],kk[1][3]) : -INFINITY) * r;
    o.z = fexp2((vm[2] & (1u<<i)) ? dot16(q0,q1,q2,q3, kk[2][0],kk[2][1],kk[2][2],kk[2][3]) : -INFINITY) * r;
    o.w = fexp2((vm[3] & (1u<<i)) ? dot16(q0,q1,q2,q3, kk[3][0],kk[3][1],kk[3][2],kk[3][3]) : -INFINITY) * r;
    *(float4*)(op + (((size_t)i) << 14)) = o;  // 64 lanes -> 1KB contiguous
  }
}

extern "C" void kernel_launch(void* const* d_in, const int* in_sizes, int n_in,
                              void* d_out, int out_size, void* d_ws, size_t ws_size,
                              hipStream_t stream)
{
  const float* qA = (const float*)d_in[0];
  const float* kA = (const float*)d_in[1];
  const void*  qm = d_in[2];
  const void*  km = d_in[3];
  float* out = (float*)d_out;

  float* partials = (float*)d_ws;                    // 64*2048 floats = 512KB
  float* R        = partials + (size_t)(LK/256)*BB*HH*NN;

  dim3 g1(LK/256, BB);             // (64, 4) = 256 blocks x 1024 threads
  k1_rowsum<<<g1, 1024, 0, stream>>>(qA, kA, qm, km, partials);
  k1_finalize<<<(BB*HH*NN)/256, 256, 0, stream>>>(partials, R);
  dim3 g2(LK/256, NN/TI2, BB);     // (64, 4, 4) = 1024 blocks x 256 threads
  k2_emit<<<g2, 256, 0, stream>>>(qA, kA, qm, km, R, out);
}